// Round 2
// baseline (199.311 us; speedup 1.0000x reference)
//
#include <hip/hip_runtime.h>
#include <hip/hip_bf16.h>

#define B_    128
#define N_    4096
#define DIM_  16
#define HID_  128
#define ROWS_ 512           // n-rows per block
#define CHUNK_ 128          // compacted rows per inner chunk
#define NTILE_ (N_ / ROWS_) // 8

typedef __bf16 bf16x2 __attribute__((ext_vector_type(2)));
typedef __bf16 bf16x8 __attribute__((ext_vector_type(8)));
typedef float floatx16 __attribute__((ext_vector_type(16)));

__device__ inline bf16x8 load_cvt8(const float* __restrict__ p) {
  const float4 u = *(const float4*)p;
  const float4 v = *(const float4*)(p + 4);
  bf16x8 r;
  r[0] = (__bf16)u.x; r[1] = (__bf16)u.y; r[2] = (__bf16)u.z; r[3] = (__bf16)u.w;
  r[4] = (__bf16)v.x; r[5] = (__bf16)v.y; r[6] = (__bf16)v.z; r[7] = (__bf16)v.w;
  return r;
}

// h1 = relu([x | ender] @ W1 + b1); h2 = relu(h1 @ W2 + b2);
// part[b, ntile, :] = sum over this block's ACTIVE (mask=1) rows of h2.
// Feature permutation for stage A storage: storage slot s (0..127):
//   c = s>>5 (tile), n = s&31;  feat(s) = (c>>1)*64 + 2*n + (c&1)
// so a wave's two tiles {2p, 2p+1} give lane n adjacent feats 64p+2n, 64p+2n+1
// -> packed b32 h1 stores (no ds_write_b16 same-dword conflicts).
__global__ __launch_bounds__(256, 3) void edge_kernel(
    const float* __restrict__ x, const float* __restrict__ adj,
    const float* __restrict__ W1, const float* __restrict__ b1,
    const float* __restrict__ W2, const float* __restrict__ b2,
    const int* __restrict__ ip, float* __restrict__ part)
{
  __shared__ __align__(16) __bf16 sW1T[HID_][24];    // permuted storage order
  __shared__ __align__(16) __bf16 sH1[CHUNK_][136];  // true-feature order, stride 68 dw = 4 mod 32
  __shared__ float sB1[HID_];                        // storage order (ender-folded)
  __shared__ float sAcc[HID_];
  __shared__ float sEnder[DIM_];
  __shared__ int   sIdx[ROWS_];
  __shared__ int   sCnt;

  const int t  = threadIdx.x;
  const int b  = blockIdx.y;
  const int n0 = blockIdx.x * ROWS_;
  const int ii = __ldg(ip);

  if (t == 0) sCnt = 0;
  if (t < DIM_) sEnder[t] = x[((size_t)b * N_ + ii) * DIM_ + t];
  __syncthreads();

  // compact active row indices (order irrelevant for a sum)
  #pragma unroll
  for (int r = t; r < ROWS_; r += 256)
    if (adj[n0 + r] != 0.f) sIdx[atomicAdd(&sCnt, 1)] = n0 + r;

  // stage-A weights, permuted storage order
  for (int e = t; e < DIM_ * HID_; e += 256) {
    int s = e & 127, k = e >> 7;
    int c = s >> 5, n = s & 31;
    int f = ((c >> 1) << 6) + 2 * n + (c & 1);
    sW1T[s][k] = (__bf16)W1[k * HID_ + f];
  }
  __syncthreads();
  const int cnt = sCnt;
  const int nch = (cnt + CHUNK_ - 1) / CHUNK_;
  for (int p = cnt + t; p < nch * CHUNK_; p += 256) sIdx[p] = n0;  // pad, excluded later
  if (t < HID_) {
    int c = t >> 5, n = t & 31;
    int f = ((c >> 1) << 6) + 2 * n + (c & 1);
    float s = b1[f];                    // fold ender @ W1[16:32,:] into bias (fp32)
    #pragma unroll
    for (int k = 0; k < DIM_; ++k) s += sEnder[k] * W1[(DIM_ + k) * HID_ + f];
    sB1[t] = s;
    sAcc[t] = 0.f;
  }

  const int wave = t >> 6, lane = t & 63;
  const int half = lane >> 5, l31 = lane & 31;
  const int rt0 = (wave >> 1) << 1;   // row-tile pair base (0 or 2)
  const int p4  = wave & 1;           // col-pair (stage A storage tiles 2p,2p+1; stage B cols 64p..)
  const int col0 = p4 * 64 + l31, col1 = col0 + 32;   // stage-B true output features
  const int sc0  = p4 * 64 + 2 * l31;                 // packed h1 store base

  // W2 B-fragments in registers, once (coalesced 128B lines across l31)
  bf16x8 w2a[8], w2b[8];
  #pragma unroll
  for (int s = 0; s < 8; ++s) {
    const int kb = s * 16 + half * 8;
    bf16x8 fa, fb;
    #pragma unroll
    for (int j = 0; j < 8; ++j) {
      fa[j] = (__bf16)W2[(kb + j) * HID_ + col0];
      fb[j] = (__bf16)W2[(kb + j) * HID_ + col1];
    }
    w2a[s] = fa; w2b[s] = fb;
  }
  const float bv0 = b2[col0], bv1 = b2[col1];
  __syncthreads();

  // chunk-invariant stage-A fragments / biases
  const bf16x8 bf0 = *(const bf16x8*)&sW1T[p4 * 64      + l31][half * 8];
  const bf16x8 bf1 = *(const bf16x8*)&sW1T[p4 * 64 + 32 + l31][half * 8];
  const float bva0 = sB1[p4 * 64 + l31], bva1 = sB1[p4 * 64 + 32 + l31];

  float p0 = 0.f, p1 = 0.f;   // per-lane column partial sums, persist across chunks

  for (int c = 0; c < nch; ++c) {
    const int cb = c * CHUNK_;
    __syncthreads();   // previous chunk's stage-B readers done with sH1

    // ---------- stage A: gathered rows, K=16, packed bf16x2 stores ----------
    #pragma unroll
    for (int dr = 0; dr < 2; ++dr) {
      const int rt = rt0 + dr;
      const int idx = sIdx[cb + rt * 32 + l31];
      const bf16x8 af = load_cvt8(&x[((size_t)b * N_ + idx) * DIM_ + half * 8]);
      floatx16 a0, a1;
      #pragma unroll
      for (int r = 0; r < 16; ++r) { a0[r] = bva0; a1[r] = bva1; }
      a0 = __builtin_amdgcn_mfma_f32_32x32x16_bf16(af, bf0, a0, 0, 0, 0);
      a1 = __builtin_amdgcn_mfma_f32_32x32x16_bf16(af, bf1, a1, 0, 0, 0);
      #pragma unroll
      for (int r = 0; r < 16; ++r) {
        const int row = rt * 32 + (r & 3) + ((r >> 2) << 3) + (half << 2);
        bf16x2 pv;
        pv[0] = (__bf16)fmaxf(a0[r], 0.f);
        pv[1] = (__bf16)fmaxf(a1[r], 0.f);
        *(bf16x2*)&sH1[row][sc0] = pv;
      }
    }
    __syncthreads();   // sH1 ready

    // ---------- stage B: K=128, 2x2 register blocking, W2 from registers ----------
    floatx16 c00, c01, c10, c11;
    #pragma unroll
    for (int r = 0; r < 16; ++r) { c00[r] = bv0; c01[r] = bv1; c10[r] = bv0; c11[r] = bv1; }
    #pragma unroll
    for (int s = 0; s < 8; ++s) {
      const int ko = s * 16 + half * 8;
      const bf16x8 A0 = *(const bf16x8*)&sH1[rt0 * 32      + l31][ko];
      const bf16x8 A1 = *(const bf16x8*)&sH1[rt0 * 32 + 32 + l31][ko];
      c00 = __builtin_amdgcn_mfma_f32_32x32x16_bf16(A0, w2a[s], c00, 0, 0, 0);
      c01 = __builtin_amdgcn_mfma_f32_32x32x16_bf16(A0, w2b[s], c01, 0, 0, 0);
      c10 = __builtin_amdgcn_mfma_f32_32x32x16_bf16(A1, w2a[s], c10, 0, 0, 0);
      c11 = __builtin_amdgcn_mfma_f32_32x32x16_bf16(A1, w2b[s], c11, 0, 0, 0);
    }
    // relu + validity-guarded row-sum (compacted rows all have mask 1)
    if (cb + CHUNK_ <= cnt) {           // full chunk: every row valid
      #pragma unroll
      for (int r = 0; r < 16; ++r) {
        p0 += fmaxf(c00[r], 0.f) + fmaxf(c10[r], 0.f);
        p1 += fmaxf(c01[r], 0.f) + fmaxf(c11[r], 0.f);
      }
    } else {                            // tail chunk: guard padded rows
      #pragma unroll
      for (int r = 0; r < 16; ++r) {
        const int q0 = cb + rt0 * 32 + (r & 3) + ((r >> 2) << 3) + (half << 2);
        const int q1 = q0 + 32;
        if (q0 < cnt) { p0 += fmaxf(c00[r], 0.f); p1 += fmaxf(c01[r], 0.f); }
        if (q1 < cnt) { p0 += fmaxf(c10[r], 0.f); p1 += fmaxf(c11[r], 0.f); }
      }
    }
  }

  // two waves share each column: combine via LDS, then one plain store per block
  atomicAdd(&sAcc[col0], p0);
  atomicAdd(&sAcc[col1], p1);
  __syncthreads();
  if (t < HID_) part[((size_t)b * NTILE_ + blockIdx.x) * HID_ + t] = sAcc[t];
}

// acc = sum partials; h3 = relu(acc@W3+b3); h4 = relu(h3@W4+b4);
// out = [x[:,i,:] | h4] @ W5 + b5   (all fp32, exact)
__global__ void tail_kernel(
    const float* __restrict__ x, const float* __restrict__ part,
    const float* __restrict__ W3, const float* __restrict__ b3,
    const float* __restrict__ W4, const float* __restrict__ b4,
    const float* __restrict__ W5, const float* __restrict__ b5,
    const int* __restrict__ ip, float* __restrict__ out)
{
  const int b = blockIdx.x, t = threadIdx.x;   // 128 threads
  __shared__ float s0[HID_], s1[HID_], s2[HID_], se[DIM_];
  const int ii = __ldg(ip);
  if (t < DIM_) se[t] = x[((size_t)b * N_ + ii) * DIM_ + t];
  float a = 0.f;
  #pragma unroll
  for (int p = 0; p < NTILE_; ++p) a += part[((size_t)b * NTILE_ + p) * HID_ + t];
  s0[t] = a;
  __syncthreads();
  float v = b3[t];
  #pragma unroll 16
  for (int k = 0; k < HID_; ++k) v += s0[k] * W3[k * HID_ + t];
  s1[t] = fmaxf(v, 0.f);
  __syncthreads();
  float w = b4[t];
  #pragma unroll 16
  for (int k = 0; k < HID_; ++k) w += s1[k] * W4[k * HID_ + t];
  s2[t] = fmaxf(w, 0.f);
  __syncthreads();
  if (t < DIM_) {
    float o = b5[t];
    #pragma unroll
    for (int k = 0; k < DIM_; ++k) o += se[k] * W5[k * DIM_ + t];
    #pragma unroll 16
    for (int k = 0; k < HID_; ++k) o += s2[k] * W5[(DIM_ + k) * DIM_ + t];
    out[b * DIM_ + t] = o;
  }
}

extern "C" void kernel_launch(void* const* d_in, const int* in_sizes, int n_in,
                              void* d_out, int out_size, void* d_ws, size_t ws_size,
                              hipStream_t stream) {
  const float* x   = (const float*)d_in[0];
  const float* adj = (const float*)d_in[1];
  const float* W1  = (const float*)d_in[2];   // W_n2e [32,128]
  const float* b1  = (const float*)d_in[3];
  const float* W2  = (const float*)d_in[4];   // W_e2e [128,128]
  const float* b2  = (const float*)d_in[5];
  const float* W3  = (const float*)d_in[6];   // W_e2n
  const float* b3  = (const float*)d_in[7];
  const float* W4  = (const float*)d_in[8];   // W_n2n
  const float* b4  = (const float*)d_in[9];
  const float* W5  = (const float*)d_in[10];  // W_out [144,16]
  const float* b5  = (const float*)d_in[11];
  const int*   ip  = (const int*)d_in[12];
  float* out  = (float*)d_out;
  float* part = (float*)d_ws;                 // [B, NTILE, HID] fp32 partials (all written)

  edge_kernel<<<dim3(NTILE_, B_), 256, 0, stream>>>(x, adj, W1, b1, W2, b2, ip, part);
  tail_kernel<<<B_, HID_, 0, stream>>>(x, part, W3, b3, W4, b4, W5, b5, ip, out);
}

// Round 3
// 128.110 us; speedup vs baseline: 1.5558x; 1.5558x over previous
//
#include <hip/hip_runtime.h>
#include <hip/hip_bf16.h>

#define B_    128
#define N_    4096
#define DIM_  16
#define HID_  128
#define NT_   4             // grid.x tiles
#define ROWS_ (N_ / NT_)    // 1024 adj rows per block

typedef __bf16 bf16x2 __attribute__((ext_vector_type(2)));
typedef __bf16 bf16x8 __attribute__((ext_vector_type(8)));
typedef float floatx16 __attribute__((ext_vector_type(16)));
typedef unsigned int u32;
typedef unsigned int u32x4 __attribute__((ext_vector_type(4)));

__device__ inline bf16x8 load_cvt8(const float* __restrict__ p) {
  const float4 u = *(const float4*)p;
  const float4 v = *(const float4*)(p + 4);
  bf16x8 r;
  r[0] = (__bf16)u.x; r[1] = (__bf16)u.y; r[2] = (__bf16)u.z; r[3] = (__bf16)u.w;
  r[4] = (__bf16)v.x; r[5] = (__bf16)v.y; r[6] = (__bf16)v.z; r[7] = (__bf16)v.w;
  return r;
}

__device__ inline u32 pk2(float a, float b) {
  bf16x2 p; p[0] = (__bf16)a; p[1] = (__bf16)b;
  return __builtin_bit_cast(u32, p);
}

// Barrier-free edge stage. Swapped stage A: C_ft = W1_ft^T @ x^T  (m=feat on regs,
// n=row on lane&31) + bias via spare-K MFMA. Half-swap shuffles rearrange C_ft into
// stage-B A-frags (m=row on lane&31, k=feat). Stage B: A=h1, B=W2 (XOR-swizzled LDS).
// Per-lane col sums -> LDS atomics once at the end. No __syncthreads in the main loop.
__global__ __launch_bounds__(256, 2) void edge_kernel(
    const float* __restrict__ x, const float* __restrict__ adj,
    const float* __restrict__ W1, const float* __restrict__ b1,
    const float* __restrict__ W2, const float* __restrict__ b2,
    const int* __restrict__ ip, float* __restrict__ part)
{
  // W2^T swizzled: col c occupies 128 contiguous bf16 (16 granules of 8);
  // granule g (k=8g..8g+7) stored at granule slot g ^ (c & 15).
  __shared__ __align__(16) __bf16 sW2[HID_ * HID_];
  __shared__ int   sIdx[ROWS_ + 32];
  __shared__ float sAcc[HID_];
  __shared__ float sEnder[DIM_];
  __shared__ int   sCnt;

  const int t  = threadIdx.x;
  const int b  = blockIdx.y;
  const int n0 = blockIdx.x * ROWS_;
  const int ii = __ldg(ip);

  if (t == 0) sCnt = 0;
  if (t < HID_) sAcc[t] = 0.f;
  if (t < DIM_) sEnder[t] = x[((size_t)b * N_ + ii) * DIM_ + t];
  __syncthreads();

  // compact active rows (order irrelevant for the sum)
  #pragma unroll
  for (int r = t; r < ROWS_; r += 256)
    if (adj[n0 + r] != 0.f) sIdx[atomicAdd(&sCnt, 1)] = n0 + r;

  // stage W2^T into LDS, bf16, XOR-swizzled granules
  #pragma unroll
  for (int e = 0; e < 8; ++e) {
    const int G = t * 8 + e;            // granule id: c = G>>4, g = G&15
    const int c = G >> 4, g = G & 15;
    bf16x8 v;
    #pragma unroll
    for (int j = 0; j < 8; ++j) v[j] = (__bf16)W2[((g << 3) + j) * HID_ + c];
    *(bf16x8*)&sW2[(c << 7) + ((g ^ (c & 15)) << 3)] = v;
  }

  const int wave = t >> 6, lane = t & 63;
  const int half = lane >> 5, l31 = lane & 31;

  // W1^T A-frags (m=feat=l31+32ft, k=half*8+j), rows 0..15 of W1 (starter half)
  bf16x8 w1f[NT_];
  #pragma unroll
  for (int ft = 0; ft < 4; ++ft) {
    bf16x8 v;
    #pragma unroll
    for (int j = 0; j < 8; ++j)
      v[j] = (__bf16)W1[(half * 8 + j) * HID_ + (ft * 32 + l31)];
    w1f[ft] = v;
  }

  // fold ender @ W1[16:32,:] + b1 into per-feature bias; deliver via spare-K MFMA
  // (k=0: bf16(bias), k=1: bf16 residual -> near-fp32 accuracy)
  bf16x8 a2f[4], onef;
  {
    #pragma unroll
    for (int j = 0; j < 8; ++j) onef[j] = (__bf16)0.f;
    if (half == 0) { onef[0] = (__bf16)1.f; onef[1] = (__bf16)1.f; }
    #pragma unroll
    for (int ft = 0; ft < 4; ++ft) {
      const int f = ft * 32 + l31;
      float s = b1[f];
      #pragma unroll
      for (int k = 0; k < DIM_; ++k) s += sEnder[k] * W1[(DIM_ + k) * HID_ + f];
      bf16x8 v;
      #pragma unroll
      for (int j = 0; j < 8; ++j) v[j] = (__bf16)0.f;
      if (half == 0) {
        const __bf16 hi = (__bf16)s;
        v[0] = hi;
        v[1] = (__bf16)(s - (float)hi);
      }
      a2f[ft] = v;
    }
  }

  const float bv0 = b2[l31], bv1 = b2[32 + l31], bv2 = b2[64 + l31], bv3 = b2[96 + l31];

  __syncthreads();                       // sIdx/sCnt/sW2 ready
  const int cnt = sCnt;
  const int nch = (cnt + 31) >> 5;
  for (int p = cnt + t; p < nch * 32; p += 256) sIdx[p] = n0;   // pad (guarded out)
  __syncthreads();

  float sum0 = 0.f, sum1 = 0.f, sum2 = 0.f, sum3 = 0.f;
  floatx16 zf;
  #pragma unroll
  for (int r = 0; r < 16; ++r) zf[r] = 0.f;

  for (int cb = wave * 32; cb < nch * 32; cb += 128) {
    const int row = sIdx[cb + l31];
    const bf16x8 xf = load_cvt8(&x[((size_t)b * N_ + row) * DIM_ + half * 8]);

    // ---- stage A: h1^T tiles (feat on regs, row on l31), bias folded via MFMA ----
    bf16x8 af[8];                        // stage-B A-frags, k = s*16 + half*8 + j
    #pragma unroll
    for (int ft = 0; ft < 4; ++ft) {
      floatx16 hc = __builtin_amdgcn_mfma_f32_32x32x16_bf16(w1f[ft], xf, zf, 0, 0, 0);
      hc = __builtin_amdgcn_mfma_f32_32x32x16_bf16(a2f[ft], onef, hc, 0, 0, 0);
      #pragma unroll
      for (int sg = 0; sg < 2; ++sg) {   // sigma: low/high 16-feat group of this tile
        float e0 = fmaxf(hc[8*sg+0], 0.f), e1 = fmaxf(hc[8*sg+1], 0.f);
        float e2 = fmaxf(hc[8*sg+2], 0.f), e3 = fmaxf(hc[8*sg+3], 0.f);
        float e4 = fmaxf(hc[8*sg+4], 0.f), e5 = fmaxf(hc[8*sg+5], 0.f);
        float e6 = fmaxf(hc[8*sg+6], 0.f), e7 = fmaxf(hc[8*sg+7], 0.f);
        const u32 lo0 = pk2(e0, e1), lo1 = pk2(e2, e3);
        const u32 hi0 = pk2(e4, e5), hi1 = pk2(e6, e7);
        const u32 sA = half ? lo0 : hi0;
        const u32 sB = half ? lo1 : hi1;
        const u32 rA = (u32)__shfl_xor((int)sA, 32);
        const u32 rB = (u32)__shfl_xor((int)sB, 32);
        u32x4 d;
        d[0] = half ? rA : lo0;
        d[1] = half ? rB : lo1;
        d[2] = half ? hi0 : rA;
        d[3] = half ? hi1 : rB;
        af[ft * 2 + sg] = __builtin_bit_cast(bf16x8, d);
      }
    }

    // ---- stage B: 32 rows x 128 cols, K=128; B-frags from swizzled LDS ----
    floatx16 c0 = zf, c1 = zf, c2 = zf, c3 = zf;
    #pragma unroll
    for (int s = 0; s < 8; ++s) {
      const int gp = ((s << 1) + half) ^ (l31 & 15);
      const __bf16* wp = &sW2[(l31 << 7) + (gp << 3)];
      const bf16x8 wb0 = *(const bf16x8*)(wp);
      const bf16x8 wb1 = *(const bf16x8*)(wp + (32 << 7));
      const bf16x8 wb2 = *(const bf16x8*)(wp + (64 << 7));
      const bf16x8 wb3 = *(const bf16x8*)(wp + (96 << 7));
      c0 = __builtin_amdgcn_mfma_f32_32x32x16_bf16(af[s], wb0, c0, 0, 0, 0);
      c1 = __builtin_amdgcn_mfma_f32_32x32x16_bf16(af[s], wb1, c1, 0, 0, 0);
      c2 = __builtin_amdgcn_mfma_f32_32x32x16_bf16(af[s], wb2, c2, 0, 0, 0);
      c3 = __builtin_amdgcn_mfma_f32_32x32x16_bf16(af[s], wb3, c3, 0, 0, 0);
    }

    // ---- epilogue: bias + relu + row-sum (rows on regs: m=(r&3)+8*(r>>2)+4*half) ----
    if (cb + 32 <= cnt) {
      #pragma unroll
      for (int r = 0; r < 16; ++r) {
        sum0 += fmaxf(c0[r] + bv0, 0.f);
        sum1 += fmaxf(c1[r] + bv1, 0.f);
        sum2 += fmaxf(c2[r] + bv2, 0.f);
        sum3 += fmaxf(c3[r] + bv3, 0.f);
      }
    } else {
      #pragma unroll
      for (int r = 0; r < 16; ++r) {
        const int q = cb + (r & 3) + ((r >> 2) << 3) + (half << 2);
        if (q < cnt) {
          sum0 += fmaxf(c0[r] + bv0, 0.f);
          sum1 += fmaxf(c1[r] + bv1, 0.f);
          sum2 += fmaxf(c2[r] + bv2, 0.f);
          sum3 += fmaxf(c3[r] + bv3, 0.f);
        }
      }
    }
  }

  // fold halves, one LDS atomic per (col, wave)
  sum0 += __shfl_xor(sum0, 32);
  sum1 += __shfl_xor(sum1, 32);
  sum2 += __shfl_xor(sum2, 32);
  sum3 += __shfl_xor(sum3, 32);
  if (half == 0) {
    atomicAdd(&sAcc[l31],      sum0);
    atomicAdd(&sAcc[32 + l31], sum1);
    atomicAdd(&sAcc[64 + l31], sum2);
    atomicAdd(&sAcc[96 + l31], sum3);
  }
  __syncthreads();
  if (t < HID_) part[((size_t)b * NT_ + blockIdx.x) * HID_ + t] = sAcc[t];
}

// acc = sum partials; h3 = relu(acc@W3+b3); h4 = relu(h3@W4+b4);
// out = [x[:,i,:] | h4] @ W5 + b5   (all fp32, exact)
__global__ void tail_kernel(
    const float* __restrict__ x, const float* __restrict__ part,
    const float* __restrict__ W3, const float* __restrict__ b3,
    const float* __restrict__ W4, const float* __restrict__ b4,
    const float* __restrict__ W5, const float* __restrict__ b5,
    const int* __restrict__ ip, float* __restrict__ out)
{
  const int b = blockIdx.x, t = threadIdx.x;   // 128 threads
  __shared__ float s0[HID_], s1[HID_], s2[HID_], se[DIM_];
  const int ii = __ldg(ip);
  if (t < DIM_) se[t] = x[((size_t)b * N_ + ii) * DIM_ + t];
  float a = 0.f;
  #pragma unroll
  for (int p = 0; p < NT_; ++p) a += part[((size_t)b * NT_ + p) * HID_ + t];
  s0[t] = a;
  __syncthreads();
  float v = b3[t];
  #pragma unroll 16
  for (int k = 0; k < HID_; ++k) v += s0[k] * W3[k * HID_ + t];
  s1[t] = fmaxf(v, 0.f);
  __syncthreads();
  float w = b4[t];
  #pragma unroll 16
  for (int k = 0; k < HID_; ++k) w += s1[k] * W4[k * HID_ + t];
  s2[t] = fmaxf(w, 0.f);
  __syncthreads();
  if (t < DIM_) {
    float o = b5[t];
    #pragma unroll
    for (int k = 0; k < DIM_; ++k) o += se[k] * W5[k * DIM_ + t];
    #pragma unroll 16
    for (int k = 0; k < HID_; ++k) o += s2[k] * W5[(DIM_ + k) * DIM_ + t];
    out[b * DIM_ + t] = o;
  }
}

extern "C" void kernel_launch(void* const* d_in, const int* in_sizes, int n_in,
                              void* d_out, int out_size, void* d_ws, size_t ws_size,
                              hipStream_t stream) {
  const float* x   = (const float*)d_in[0];
  const float* adj = (const float*)d_in[1];
  const float* W1  = (const float*)d_in[2];   // W_n2e [32,128]
  const float* b1  = (const float*)d_in[3];
  const float* W2  = (const float*)d_in[4];   // W_e2e [128,128]
  const float* b2  = (const float*)d_in[5];
  const float* W3  = (const float*)d_in[6];   // W_e2n
  const float* b3  = (const float*)d_in[7];
  const float* W4  = (const float*)d_in[8];   // W_n2n
  const float* b4  = (const float*)d_in[9];
  const float* W5  = (const float*)d_in[10];  // W_out [144,16]
  const float* b5  = (const float*)d_in[11];
  const int*   ip  = (const int*)d_in[12];
  float* out  = (float*)d_out;
  float* part = (float*)d_ws;                 // [B, NT_, HID] fp32 partials

  edge_kernel<<<dim3(NT_, B_), 256, 0, stream>>>(x, adj, W1, b1, W2, b2, ip, part);
  tail_kernel<<<B_, HID_, 0, stream>>>(x, part, W3, b3, W4, b4, W5, b5, ip, out);
}